// Round 1
// baseline (635.455 us; speedup 1.0000x reference)
//
#include <hip/hip_runtime.h>
#include <hip/hip_bf16.h>

#define B_ 8
#define T_ 4096
#define C_ 256
#define H_ 256
#define K_ 3

// ws layout:
//  [0]                : wf_t  (C*K*H floats)  weights transposed to [c][k][h]
//  [CKH]              : wz_t  (C*K*H floats)
//  [2*CKH]            : gates (B*T*H float2)  {a = z*(1-f), f} for t'=0..T-1 (global time t'+1)
#define CKH (C_ * K_ * H_)

__device__ __forceinline__ float sigm(float x) {
    return 1.0f / (1.0f + __expf(-x));
}

__global__ __launch_bounds__(256) void wtrans_kernel(const float* __restrict__ fw,
                                                     const float* __restrict__ zw,
                                                     float* __restrict__ wf_t,
                                                     float* __restrict__ wz_t) {
    int i = blockIdx.x * 256 + threadIdx.x;   // output index over C*K*H
    if (i >= CKH) return;
    int h = i & (H_ - 1);
    int ck = i >> 8;          // c*3 + k
    int c = ck / K_;
    int k = ck - c * K_;
    int src = (h * C_ + c) * K_ + k;
    wf_t[i] = fw[src];
    wz_t[i] = zw[src];
}

// Each block: one b, 32 consecutive t rows, all 256 h (one thread per h).
__global__ __launch_bounds__(256) void conv_gates_kernel(const float* __restrict__ x,
                                                         const float* __restrict__ wf_t,
                                                         const float* __restrict__ wz_t,
                                                         const float* __restrict__ fb,
                                                         const float* __restrict__ zb,
                                                         float2* __restrict__ gates) {
    __shared__ float xs[34 * 256];
    const int b = blockIdx.y;
    const int t0 = blockIdx.x * 32;
    const int tid = threadIdx.x;

    // Stage x[b, t0-1 .. t0+32, :] (zero padded) into LDS. 34 rows * 64 float4.
    for (int idx = tid; idx < 34 * 64; idx += 256) {
        int row = idx >> 6;
        int c4 = idx & 63;
        int t = t0 - 1 + row;
        float4 v = make_float4(0.f, 0.f, 0.f, 0.f);
        if (t >= 0 && t < T_)
            v = *(const float4*)(x + (((size_t)b * T_ + t) * C_) + c4 * 4);
        *(float4*)(xs + row * 256 + c4 * 4) = v;
    }
    __syncthreads();

    const int h = tid;
    float accf[32], accz[32];
    const float fbi = fb[h];
    const float zbi = zb[h];
#pragma unroll
    for (int tt = 0; tt < 32; ++tt) { accf[tt] = fbi; accz[tt] = zbi; }

#pragma unroll 1
    for (int c = 0; c < C_; ++c) {
        float xr[34];
#pragma unroll
        for (int j = 0; j < 34; ++j) xr[j] = xs[j * 256 + c];   // broadcast reads
        const float* wfp = wf_t + c * (K_ * H_) + h;            // coalesced
        const float* wzp = wz_t + c * (K_ * H_) + h;
        float wf0 = wfp[0], wf1 = wfp[256], wf2 = wfp[512];
        float wz0 = wzp[0], wz1 = wzp[256], wz2 = wzp[512];
#pragma unroll
        for (int tt = 0; tt < 32; ++tt) {
            accf[tt] = fmaf(xr[tt + 2], wf2, fmaf(xr[tt + 1], wf1, fmaf(xr[tt], wf0, accf[tt])));
            accz[tt] = fmaf(xr[tt + 2], wz2, fmaf(xr[tt + 1], wz1, fmaf(xr[tt], wz0, accz[tt])));
        }
    }

    float2* gp = gates + ((size_t)b * T_ + t0) * H_ + h;
#pragma unroll
    for (int tt = 0; tt < 32; ++tt) {
        float f = sigm(accf[tt]);
        float z = sigm(accz[tt]);
        gp[tt * H_] = make_float2(z * (1.0f - f), f);
    }
}

// One thread per (b,h): sequential recurrence out_t = a_t + f_{t-1}*out_{t-1}.
__global__ __launch_bounds__(256) void scan_kernel(const float2* __restrict__ gates,
                                                   const float* __restrict__ init_f,
                                                   const float* __restrict__ init_z,
                                                   float* __restrict__ out) {
    const int b = blockIdx.x;
    const int h = threadIdx.x;

    float f0 = sigm(init_f[b * H_ + h]);
    float z0 = sigm(init_z[b * H_ + h]);
    float o = z0 * (1.0f - f0);
    out[((size_t)b * (T_ + 1)) * H_ + h] = o;
    float fprev = f0;

    const float2* g = gates + (size_t)b * T_ * H_ + h;
    float* op = out + ((size_t)b * (T_ + 1) + 1) * H_ + h;
#pragma unroll 8
    for (int t = 0; t < T_; ++t) {
        float2 af = g[(size_t)t * H_];
        o = af.x + fprev * o;
        op[(size_t)t * H_] = o;
        fprev = af.y;
    }
}

extern "C" void kernel_launch(void* const* d_in, const int* in_sizes, int n_in,
                              void* d_out, int out_size, void* d_ws, size_t ws_size,
                              hipStream_t stream) {
    const float* inputs = (const float*)d_in[0];   // [B,T,C]
    const float* init_f = (const float*)d_in[1];   // [B,H]
    const float* init_z = (const float*)d_in[2];   // [B,H]
    const float* f_w    = (const float*)d_in[3];   // [H,C,K]
    const float* f_b    = (const float*)d_in[4];   // [H]
    const float* z_w    = (const float*)d_in[5];   // [H,C,K]
    const float* z_b    = (const float*)d_in[6];   // [H]
    float* out = (float*)d_out;                    // [B,T+1,H]

    float* ws = (float*)d_ws;
    float* wf_t = ws;
    float* wz_t = ws + CKH;
    float2* gates = (float2*)(ws + 2 * CKH);

    wtrans_kernel<<<(CKH + 255) / 256, 256, 0, stream>>>(f_w, z_w, wf_t, wz_t);

    dim3 cgrid(T_ / 32, B_, 1);
    conv_gates_kernel<<<cgrid, 256, 0, stream>>>(inputs, wf_t, wz_t, f_b, z_b, gates);

    scan_kernel<<<B_, H_, 0, stream>>>(gates, init_f, init_z, out);
}

// Round 2
// 452.262 us; speedup vs baseline: 1.4051x; 1.4051x over previous
//
#include <hip/hip_runtime.h>
#include <hip/hip_bf16.h>

#define B_ 8
#define T_ 4096
#define C_ 256
#define H_ 256
#define K_ 3
#define NC 128          // number of time chunks
#define TC 32           // timesteps per chunk
#define CKH (C_ * K_ * H_)

// ws layout (floats):
//  [0]                      wf_t  CKH            weights [c][k][h]
//  [CKH]                    wz_t  CKH
//  [2*CKH]                  AP    B*T*H float2   {A_j, P_j} at [b, g-1, h], g=global out idx
//  [2*CKH + 2*B*T*H]        sin   B*NC*H         chunk entry states

__device__ __forceinline__ float sigm(float x) {
    return 1.0f / (1.0f + __expf(-x));
}

__global__ __launch_bounds__(256) void wtrans_kernel(const float* __restrict__ fw,
                                                     const float* __restrict__ zw,
                                                     float* __restrict__ wf_t,
                                                     float* __restrict__ wz_t) {
    int i = blockIdx.x * 256 + threadIdx.x;   // over C*K*H
    if (i >= CKH) return;
    int h = i & (H_ - 1);
    int ck = i >> 8;          // c*3 + k
    int c = ck / K_;
    int k = ck - c * K_;
    int src = (h * C_ + c) * K_ + k;
    wf_t[i] = fw[src];
    wz_t[i] = zw[src];
}

// Block (chunk c0, batch b): conv rows t0-1 .. t0+31 (33 rows), thread per h.
// Epilogue computes local affine scan {A_j, P_j} for j=1..32 and writes float2.
__global__ __launch_bounds__(256) void conv_scan_kernel(const float* __restrict__ x,
                                                        const float* __restrict__ wf_t,
                                                        const float* __restrict__ wz_t,
                                                        const float* __restrict__ fb,
                                                        const float* __restrict__ zb,
                                                        const float* __restrict__ init_f,
                                                        float2* __restrict__ AP) {
    __shared__ float xs[35 * 256];
    const int b = blockIdx.y;
    const int c0 = blockIdx.x;
    const int t0 = c0 * TC;
    const int tid = threadIdx.x;

    // Stage x[b, t0-2 .. t0+32, :] (zero padded) into LDS: 35 rows.
    for (int idx = tid; idx < 35 * 64; idx += 256) {
        int row = idx >> 6;
        int c4 = idx & 63;
        int t = t0 - 2 + row;
        float4 v = make_float4(0.f, 0.f, 0.f, 0.f);
        if (t >= 0 && t < T_)
            v = *(const float4*)(x + (((size_t)b * T_ + t) * C_) + c4 * 4);
        *(float4*)(xs + row * 256 + c4 * 4) = v;
    }
    __syncthreads();

    const int h = tid;
    float accf[33], accz[33];
    const float fbi = fb[h];
    const float zbi = zb[h];
#pragma unroll
    for (int r = 0; r < 33; ++r) { accf[r] = fbi; accz[r] = zbi; }

#pragma unroll 1
    for (int c = 0; c < C_; ++c) {
        float xr[35];
#pragma unroll
        for (int j = 0; j < 35; ++j) xr[j] = xs[j * 256 + c];   // broadcast reads
        const float* wfp = wf_t + c * (K_ * H_) + h;            // coalesced, L2-resident
        const float* wzp = wz_t + c * (K_ * H_) + h;
        float wf0 = wfp[0], wf1 = wfp[256], wf2 = wfp[512];
        float wz0 = wzp[0], wz1 = wzp[256], wz2 = wzp[512];
#pragma unroll
        for (int r = 0; r < 33; ++r) {
            accf[r] = fmaf(xr[r + 2], wf2, fmaf(xr[r + 1], wf1, fmaf(xr[r], wf0, accf[r])));
            accz[r] = fmaf(xr[r + 2], wz2, fmaf(xr[r + 1], wz1, fmaf(xr[r], wz0, accz[r])));
        }
    }

    // Local affine scan. Row r holds gates at global index t0+r.
    // out_{t0+j} = A_j + P_j * out_{t0};  A_j = a_{t0+j} + f_{t0+j-1} A_{j-1}; P_j = P_{j-1} f_{t0+j-1}.
    float f_prev = sigm(accf[0]);                 // f at global t0
    if (c0 == 0) f_prev = sigm(init_f[b * H_ + h]);   // global idx 0 comes from init state
    float A = 0.f, P = 1.f;
    float2* app = AP + ((size_t)b * T_ + t0) * H_ + h;
#pragma unroll
    for (int j = 1; j <= TC; ++j) {
        float fj = sigm(accf[j]);
        float aj = sigm(accz[j]) * (1.0f - fj);
        A = fmaf(f_prev, A, aj);
        P *= f_prev;
        app[(size_t)(j - 1) * H_] = make_float2(A, P);
        f_prev = fj;
    }
}

// Per (b,h): sequential over NC chunk summaries; writes chunk entry states + out[b,0,h].
__global__ __launch_bounds__(256) void combine_kernel(const float2* __restrict__ AP,
                                                      const float* __restrict__ init_f,
                                                      const float* __restrict__ init_z,
                                                      float* __restrict__ out,
                                                      float* __restrict__ sin_) {
    const int b = blockIdx.x;
    const int h = threadIdx.x;
    float f0 = sigm(init_f[b * H_ + h]);
    float z0 = sigm(init_z[b * H_ + h]);
    float s = z0 * (1.0f - f0);
    out[(size_t)b * (T_ + 1) * H_ + h] = s;
#pragma unroll 4
    for (int c = 0; c < NC; ++c) {
        sin_[((size_t)b * NC + c) * H_ + h] = s;
        float2 ap = AP[((size_t)b * T_ + c * TC + (TC - 1)) * H_ + h];
        s = fmaf(ap.y, s, ap.x);
    }
}

// Fully parallel fix-up: out_{t0+j} = A_j + P_j * s_chunk.
__global__ __launch_bounds__(256) void apply_kernel(const float2* __restrict__ AP,
                                                    const float* __restrict__ sin_,
                                                    float* __restrict__ out) {
    const int c = blockIdx.x;
    const int b = blockIdx.y;
    const int h = threadIdx.x;
    const int t0 = c * TC;
    const float s = sin_[((size_t)b * NC + c) * H_ + h];
    const float2* app = AP + ((size_t)b * T_ + t0) * H_ + h;
    float* op = out + ((size_t)b * (T_ + 1) + t0 + 1) * H_ + h;
#pragma unroll 8
    for (int j = 0; j < TC; ++j) {
        float2 ap = app[(size_t)j * H_];
        op[(size_t)j * H_] = fmaf(ap.y, s, ap.x);
    }
}

extern "C" void kernel_launch(void* const* d_in, const int* in_sizes, int n_in,
                              void* d_out, int out_size, void* d_ws, size_t ws_size,
                              hipStream_t stream) {
    const float* inputs = (const float*)d_in[0];   // [B,T,C]
    const float* init_f = (const float*)d_in[1];   // [B,H]
    const float* init_z = (const float*)d_in[2];   // [B,H]
    const float* f_w    = (const float*)d_in[3];   // [H,C,K]
    const float* f_b    = (const float*)d_in[4];   // [H]
    const float* z_w    = (const float*)d_in[5];   // [H,C,K]
    const float* z_b    = (const float*)d_in[6];   // [H]
    float* out = (float*)d_out;                    // [B,T+1,H]

    float* ws = (float*)d_ws;
    float* wf_t = ws;
    float* wz_t = ws + CKH;
    float2* AP = (float2*)(ws + 2 * CKH);
    float* sin_ = ws + 2 * CKH + 2 * (size_t)B_ * T_ * H_;

    wtrans_kernel<<<(CKH + 255) / 256, 256, 0, stream>>>(f_w, z_w, wf_t, wz_t);

    dim3 cgrid(NC, B_, 1);
    conv_scan_kernel<<<cgrid, 256, 0, stream>>>(inputs, wf_t, wz_t, f_b, z_b, init_f, AP);

    combine_kernel<<<B_, H_, 0, stream>>>(AP, init_f, init_z, out, sin_);

    dim3 agrid(NC, B_, 1);
    apply_kernel<<<agrid, 256, 0, stream>>>(AP, sin_, out);
}

// Round 3
// 110.718 us; speedup vs baseline: 5.7394x; 4.0848x over previous
//
#include <hip/hip_runtime.h>
#include <hip/hip_bf16.h>

#define B_ 8
#define T_ 4096
#define C_ 256
#define H_ 256
#define K_ 3
#define NC 128          // time chunks for the scan
#define TC 32           // timesteps per chunk
#define WFRAG_ELEMS (24 * 32 * 64 * 8)   // [ks][ntg][lane][j] bf16

typedef __attribute__((ext_vector_type(8))) __bf16 bf16x8;
typedef __attribute__((ext_vector_type(4))) float f32x4;

__device__ __forceinline__ float sigm(float x) { return 1.0f / (1.0f + __expf(-x)); }

__device__ __forceinline__ ushort f2bf(float f) {
    union { float f; unsigned u; } v; v.f = f;
    unsigned r = (v.u + 0x7FFFu + ((v.u >> 16) & 1u)) >> 16;
    return (ushort)r;
}
__device__ __forceinline__ float bf2f(ushort u) {
    union { unsigned u; float f; } v; v.u = ((unsigned)u) << 16; return v.f;
}

// Gather f_w,z_w into B-fragment-linear bf16 layout for mfma_f32_16x16x32_bf16.
// n = ntg*16 + (l&15)  (n<256 -> f, else z);  kappa = ks*32 + (l>>4)*8 + j = k*256 + c.
__global__ __launch_bounds__(256) void wfrag_kernel(const float* __restrict__ fw,
                                                    const float* __restrict__ zw,
                                                    ushort* __restrict__ wfrag) {
    int idx = blockIdx.x * 256 + threadIdx.x;
    if (idx >= WFRAG_ELEMS) return;
    int j   = idx & 7;
    int l   = (idx >> 3) & 63;
    int ntg = (idx >> 9) & 31;
    int ks  = idx >> 14;
    int n = ntg * 16 + (l & 15);
    int kappa = ks * 32 + (l >> 4) * 8 + j;
    int k = kappa >> 8, c = kappa & 255;
    const float* w = (n < 256) ? fw : zw;
    int h = n & 255;
    wfrag[idx] = f2bf(w[(h * C_ + c) * K_ + k]);
}

// 64t x 256h output tile per block (grid z picks f or z conv). 4 waves, each 64t x 64h.
// A (x) staged bf16 in LDS with XOR swizzle; B fragments streamed from L2-hot wfrag.
__global__ __launch_bounds__(256) void conv_mfma_kernel(const float* __restrict__ x,
                                                        const ushort* __restrict__ wfrag,
                                                        const float* __restrict__ fb,
                                                        const float* __restrict__ zb,
                                                        ushort* __restrict__ rawF,
                                                        ushort* __restrict__ rawZ) {
    __shared__ __align__(16) ushort xs[66 * 256];
    const int b = blockIdx.y, g = blockIdx.z;
    const int t0 = blockIdx.x * 64;
    const int tid = threadIdx.x;

    // Stage x[b, t0-1 .. t0+64, :] as bf16, swizzled: byte = row*512 + ((2c) ^ ((row&7)<<4))
    for (int idx = tid; idx < 66 * 64; idx += 256) {
        int row = idx >> 6;
        int c4 = (idx & 63) * 4;
        int t = t0 - 1 + row;
        float4 v = make_float4(0.f, 0.f, 0.f, 0.f);
        if (t >= 0 && t < T_) v = *(const float4*)(x + ((size_t)(b * T_ + t)) * C_ + c4);
        ushort4 w4;
        w4.x = f2bf(v.x); w4.y = f2bf(v.y); w4.z = f2bf(v.z); w4.w = f2bf(v.w);
        *(ushort4*)((char*)xs + row * 512 + ((c4 * 2) ^ ((row & 7) << 4))) = w4;
    }
    __syncthreads();

    const int wv = tid >> 6;
    const int l  = tid & 63;
    const int lr = l & 15;    // fragment row (A: m) / col (B: n)
    const int lg = l >> 4;    // k-group

    const float* bias = g ? zb : fb;
    f32x4 acc[4][4];
#pragma unroll
    for (int ni = 0; ni < 4; ++ni) {
        float bv = bias[wv * 64 + ni * 16 + lr];
        f32x4 bvv = {bv, bv, bv, bv};
#pragma unroll
        for (int mi = 0; mi < 4; ++mi) acc[mi][ni] = bvv;
    }

    const ushort* wp = wfrag + (size_t)((g * 16 + wv * 4) * 64 + l) * 8;

#pragma unroll 1
    for (int ks = 0; ks < 24; ++ks) {
        const int k = ks >> 3;                      // conv tap
        const int cb = ((ks & 7) * 32 + lg * 8) * 2;  // c byte offset
        bf16x8 afr[4];
#pragma unroll
        for (int mi = 0; mi < 4; ++mi) {
            int row = mi * 16 + lr + k;             // t_local shifted by tap
            afr[mi] = *(const bf16x8*)((const char*)xs + row * 512 + (cb ^ ((row & 7) << 4)));
        }
#pragma unroll
        for (int ni = 0; ni < 4; ++ni) {
            bf16x8 bfr = *(const bf16x8*)(wp + (size_t)(ks * 32 + ni) * 512);
#pragma unroll
            for (int mi = 0; mi < 4; ++mi)
                acc[mi][ni] = __builtin_amdgcn_mfma_f32_16x16x32_bf16(afr[mi], bfr, acc[mi][ni], 0, 0, 0);
        }
    }

    // C/D layout: col(h) = lane&15, row(t) = (lane>>4)*4 + reg.
    ushort* raw = g ? rawZ : rawF;
#pragma unroll
    for (int mi = 0; mi < 4; ++mi) {
#pragma unroll
        for (int ni = 0; ni < 4; ++ni) {
            int h = wv * 64 + ni * 16 + lr;
#pragma unroll
            for (int r = 0; r < 4; ++r) {
                int t = t0 + mi * 16 + lg * 4 + r;
                raw[((size_t)(b * T_ + t)) * H_ + h] = f2bf(acc[mi][ni][r]);
            }
        }
    }
}

// Sigmoid + per-chunk affine scan: AP[b][t0+j][h] = {A,P} for out index g = t0+j+1.
__global__ __launch_bounds__(256) void gate_scan_kernel(const ushort* __restrict__ rawF,
                                                        const ushort* __restrict__ rawZ,
                                                        const float* __restrict__ init_f,
                                                        float2* __restrict__ AP) {
    const int b = blockIdx.y, c0 = blockIdx.x;
    const int t0 = c0 * TC;
    const int h = threadIdx.x;
    const size_t base = ((size_t)b * T_ + t0) * H_ + h;
    float f_prev = (c0 == 0) ? sigm(init_f[b * H_ + h]) : sigm(bf2f(rawF[base - H_]));
    float A = 0.f, P = 1.f;
    const ushort* pF = rawF + base;
    const ushort* pZ = rawZ + base;
    float2* app = AP + base;
#pragma unroll 8
    for (int j = 0; j < TC; ++j) {
        float fj = sigm(bf2f(pF[(size_t)j * H_]));
        float aj = sigm(bf2f(pZ[(size_t)j * H_])) * (1.f - fj);
        A = fmaf(f_prev, A, aj);
        P *= f_prev;
        app[(size_t)j * H_] = make_float2(A, P);
        f_prev = fj;
    }
}

__global__ __launch_bounds__(256) void combine_kernel(const float2* __restrict__ AP,
                                                      const float* __restrict__ init_f,
                                                      const float* __restrict__ init_z,
                                                      float* __restrict__ out,
                                                      float* __restrict__ sin_) {
    const int b = blockIdx.x;
    const int h = threadIdx.x;
    float f0 = sigm(init_f[b * H_ + h]);
    float z0 = sigm(init_z[b * H_ + h]);
    float s = z0 * (1.0f - f0);
    out[(size_t)b * (T_ + 1) * H_ + h] = s;
#pragma unroll 4
    for (int c = 0; c < NC; ++c) {
        sin_[((size_t)b * NC + c) * H_ + h] = s;
        float2 ap = AP[((size_t)b * T_ + c * TC + (TC - 1)) * H_ + h];
        s = fmaf(ap.y, s, ap.x);
    }
}

__global__ __launch_bounds__(256) void apply_kernel(const float2* __restrict__ AP,
                                                    const float* __restrict__ sin_,
                                                    float* __restrict__ out) {
    const int c = blockIdx.x;
    const int b = blockIdx.y;
    const int h = threadIdx.x;
    const int t0 = c * TC;
    const float s = sin_[((size_t)b * NC + c) * H_ + h];
    const float2* app = AP + ((size_t)b * T_ + t0) * H_ + h;
    float* op = out + ((size_t)b * (T_ + 1) + t0 + 1) * H_ + h;
#pragma unroll 8
    for (int j = 0; j < TC; ++j) {
        float2 ap = app[(size_t)j * H_];
        op[(size_t)j * H_] = fmaf(ap.y, s, ap.x);
    }
}

extern "C" void kernel_launch(void* const* d_in, const int* in_sizes, int n_in,
                              void* d_out, int out_size, void* d_ws, size_t ws_size,
                              hipStream_t stream) {
    const float* inputs = (const float*)d_in[0];   // [B,T,C]
    const float* init_f = (const float*)d_in[1];   // [B,H]
    const float* init_z = (const float*)d_in[2];   // [B,H]
    const float* f_w    = (const float*)d_in[3];   // [H,C,K]
    const float* f_b    = (const float*)d_in[4];   // [H]
    const float* z_w    = (const float*)d_in[5];   // [H,C,K]
    const float* z_b    = (const float*)d_in[6];   // [H]
    float* out = (float*)d_out;                    // [B,T+1,H]

    // ws layout (bytes): wfrag 786432 | rawF 16 MB | rawZ 16 MB | AP 64 MB | sin 1 MB
    ushort* wfrag = (ushort*)d_ws;
    ushort* rawF  = wfrag + WFRAG_ELEMS;
    ushort* rawZ  = rawF + (size_t)B_ * T_ * H_;
    float2* AP    = (float2*)(rawZ + (size_t)B_ * T_ * H_);
    float*  sin_  = (float*)(AP + (size_t)B_ * T_ * H_);

    wfrag_kernel<<<(WFRAG_ELEMS + 255) / 256, 256, 0, stream>>>(f_w, z_w, wfrag);

    dim3 cgrid(T_ / 64, B_, 2);
    conv_mfma_kernel<<<cgrid, 256, 0, stream>>>(inputs, wfrag, f_b, z_b, rawF, rawZ);

    dim3 ggrid(NC, B_, 1);
    gate_scan_kernel<<<ggrid, 256, 0, stream>>>(rawF, rawZ, init_f, AP);

    combine_kernel<<<B_, H_, 0, stream>>>(AP, init_f, init_z, out, sin_);

    dim3 agrid(NC, B_, 1);
    apply_kernel<<<agrid, 256, 0, stream>>>(AP, sin_, out);
}

// Round 5
// 72.060 us; speedup vs baseline: 8.8184x; 1.5365x over previous
//
#include <hip/hip_runtime.h>
#include <hip/hip_bf16.h>

#define B_ 8
#define T_ 4096
#define C_ 256
#define H_ 256
#define K_ 3
#define NC 128          // time chunks (32 t each)
#define TC 32
#define WFRAG_ELEMS (24 * 32 * 64 * 8)   // [ks][ntg][lane][j] bf16

typedef __attribute__((ext_vector_type(8))) __bf16 bf16x8;
typedef __attribute__((ext_vector_type(4))) float f32x4;

__device__ __forceinline__ float sigm(float x) { return 1.0f / (1.0f + __expf(-x)); }

__device__ __forceinline__ ushort f2bf(float f) {
    union { float f; unsigned u; } v; v.f = f;
    return (ushort)((v.u + 0x7FFFu + ((v.u >> 16) & 1u)) >> 16);
}
__device__ __forceinline__ float bf2f(ushort u) {
    union { unsigned u; float f; } v; v.u = ((unsigned)u) << 16; return v.f;
}

// Gather f_w,z_w into B-fragment-linear bf16 layout for mfma_f32_16x16x32_bf16.
// n = ntg*16 + (l&15)  (n<256 -> f[h=n], else z[h=n-256]);  kappa = ks*32 + (l>>4)*8 + j = k*256 + c.
__global__ __launch_bounds__(256) void wfrag_kernel(const float* __restrict__ fw,
                                                    const float* __restrict__ zw,
                                                    ushort* __restrict__ wfrag) {
    int idx = blockIdx.x * 256 + threadIdx.x;
    if (idx >= WFRAG_ELEMS) return;
    int j   = idx & 7;
    int l   = (idx >> 3) & 63;
    int ntg = (idx >> 9) & 31;
    int ks  = idx >> 14;
    int n = ntg * 16 + (l & 15);
    int kappa = ks * 32 + (l >> 4) * 8 + j;
    int k = kappa >> 8, c = kappa & 255;
    const float* w = (n < 256) ? fw : zw;
    int h = n & 255;
    wfrag[idx] = f2bf(w[(h * C_ + c) * K_ + k]);
}

// ---------------------------------------------------------------------------
// Fused conv (f and z) + gates + per-chunk affine scan.
// Block: 64 t rows x 256 h, both gates. 8 waves; wave wv owns h in [wv*32, wv*32+32):
//   ni 0,1 -> f cols (ntg = wv*2+ni), ni 2,3 -> z cols (ntg = 16+wv*2+(ni-2)).
// Epilogue per 32-t chunk: sigmoid -> {a, f} to LDS transpose -> per-h serial scan
// producing packed bf16 {A_j, P'_j} (P' excludes the seam f) + f_last per chunk.
// ---------------------------------------------------------------------------
template <int P>
__device__ __forceinline__ void epi_write(f32x4 (&acc)[4][4], unsigned* buf,
                                          int lr, int lg, int h0) {
#pragma unroll
    for (int m2 = 0; m2 < 2; ++m2) {
        const int mi = 2 * P + m2;
#pragma unroll
        for (int ni = 0; ni < 2; ++ni) {
            const int h = h0 + ni * 16 + lr;
#pragma unroll
            for (int r = 0; r < 4; ++r) {
                float fv = sigm(acc[mi][ni][r]);
                float av = sigm(acc[mi][ni + 2][r]) * (1.0f - fv);
                int trow = m2 * 16 + lg * 4 + r;
                buf[trow * 256 + (h ^ ((trow << 2) & 31))] =
                    (unsigned)f2bf(av) | ((unsigned)f2bf(fv) << 16);
            }
        }
    }
}

__global__ __launch_bounds__(512, 4) void conv_scan_kernel(const float* __restrict__ x,
                                                           const ushort* __restrict__ wfrag,
                                                           const float* __restrict__ fb,
                                                           const float* __restrict__ zb,
                                                           unsigned* __restrict__ AP,
                                                           float* __restrict__ fl) {
    __shared__ __align__(16) char smem[66 * 512];   // union: xs 66 rows | buf 32x256 uint
    unsigned* buf = (unsigned*)smem;

    const int b = blockIdx.y;
    const int t0 = blockIdx.x * 64;
    const int tid = threadIdx.x;

    // Stage x[b, t0-1 .. t0+64, :] as bf16, swizzled: byte = row*512 + ((2c) ^ ((row&7)<<4))
    for (int idx = tid; idx < 66 * 64; idx += 512) {
        int row = idx >> 6;
        int c4 = (idx & 63) * 4;
        int t = t0 - 1 + row;
        float4 v = make_float4(0.f, 0.f, 0.f, 0.f);
        if (t >= 0 && t < T_) v = *(const float4*)(x + ((size_t)(b * T_ + t)) * C_ + c4);
        ushort4 w4;
        w4.x = f2bf(v.x); w4.y = f2bf(v.y); w4.z = f2bf(v.z); w4.w = f2bf(v.w);
        *(ushort4*)(smem + row * 512 + ((c4 * 2) ^ ((row & 7) << 4))) = w4;
    }
    __syncthreads();

    const int wv = tid >> 6;
    const int l  = tid & 63;
    const int lr = l & 15;
    const int lg = l >> 4;
    const int h0 = wv * 32;

    f32x4 acc[4][4];
#pragma unroll
    for (int ni = 0; ni < 4; ++ni) {
        float bv = (ni < 2 ? fb : zb)[h0 + (ni & 1) * 16 + lr];
        f32x4 bvv = {bv, bv, bv, bv};
#pragma unroll
        for (int mi = 0; mi < 4; ++mi) acc[mi][ni] = bvv;
    }

    const ushort* wb = wfrag + (size_t)l * 8;

#pragma unroll 1
    for (int ks = 0; ks < 24; ++ks) {
        const int k = ks >> 3;
        const int cb = ((ks & 7) * 32 + lg * 8) * 2;
        bf16x8 afr[4];
#pragma unroll
        for (int mi = 0; mi < 4; ++mi) {
            int row = mi * 16 + lr + k;
            afr[mi] = *(const bf16x8*)(smem + row * 512 + (cb ^ ((row & 7) << 4)));
        }
#pragma unroll
        for (int ni = 0; ni < 4; ++ni) {
            const int ntg = (ni < 2) ? (wv * 2 + ni) : (16 + wv * 2 + ni - 2);
            bf16x8 bfr = *(const bf16x8*)(wb + (size_t)ks * 16384 + (size_t)ntg * 512);
#pragma unroll
            for (int mi = 0; mi < 4; ++mi)
                acc[mi][ni] = __builtin_amdgcn_mfma_f32_16x16x32_bf16(afr[mi], bfr, acc[mi][ni], 0, 0, 0);
        }
    }

    // ---- phase 0: chunk = blockIdx.x*2, t rows t0..t0+31 (mi 0,1) ----
    __syncthreads();                       // xs dead from here; buf aliases it
    epi_write<0>(acc, buf, lr, lg, h0);
    __syncthreads();
    if (tid < 256) {
        const int h = tid;
        const int chunk = blockIdx.x * 2;
        const int r0 = chunk * TC;
        unsigned* app = AP + ((size_t)b * T_ + r0) * H_ + h;
        unsigned u = buf[0 * 256 + (h ^ 0)];
        float A = bf2f((ushort)(u & 0xffff));
        float P = 1.0f;
        float f_prev = bf2f((ushort)(u >> 16));
        app[0] = (unsigned)f2bf(A) | ((unsigned)f2bf(P) << 16);
#pragma unroll 8
        for (int j = 1; j < TC; ++j) {
            u = buf[j * 256 + (h ^ ((j << 2) & 31))];
            float a = bf2f((ushort)(u & 0xffff));
            float f = bf2f((ushort)(u >> 16));
            A = fmaf(f_prev, A, a);
            P *= f_prev;
            f_prev = f;
            app[(size_t)j * H_] = (unsigned)f2bf(A) | ((unsigned)f2bf(P) << 16);
        }
        fl[((size_t)b * NC + chunk) * H_ + h] = f_prev;
    }

    // ---- phase 1: chunk = blockIdx.x*2+1, t rows t0+32..t0+63 (mi 2,3) ----
    __syncthreads();
    epi_write<1>(acc, buf, lr, lg, h0);
    __syncthreads();
    if (tid < 256) {
        const int h = tid;
        const int chunk = blockIdx.x * 2 + 1;
        const int r0 = chunk * TC;
        unsigned* app = AP + ((size_t)b * T_ + r0) * H_ + h;
        unsigned u = buf[0 * 256 + (h ^ 0)];
        float A = bf2f((ushort)(u & 0xffff));
        float P = 1.0f;
        float f_prev = bf2f((ushort)(u >> 16));
        app[0] = (unsigned)f2bf(A) | ((unsigned)f2bf(P) << 16);
#pragma unroll 8
        for (int j = 1; j < TC; ++j) {
            u = buf[j * 256 + (h ^ ((j << 2) & 31))];
            float a = bf2f((ushort)(u & 0xffff));
            float f = bf2f((ushort)(u >> 16));
            A = fmaf(f_prev, A, a);
            P *= f_prev;
            f_prev = f;
            app[(size_t)j * H_] = (unsigned)f2bf(A) | ((unsigned)f2bf(P) << 16);
        }
        fl[((size_t)b * NC + chunk) * H_ + h] = f_prev;
    }
}

// Per (b,h): serial over chunk summaries. s~_c = fl(c-1)*s_c; s_{c+1} = A31 + P'31*s~_c.
__global__ __launch_bounds__(256) void combine_kernel(const unsigned* __restrict__ AP,
                                                      const float* __restrict__ fl,
                                                      const float* __restrict__ init_f,
                                                      const float* __restrict__ init_z,
                                                      float* __restrict__ out,
                                                      float* __restrict__ sin_) {
    const int b = blockIdx.x;
    const int h = threadIdx.x;
    float f0 = sigm(init_f[b * H_ + h]);
    float z0 = sigm(init_z[b * H_ + h]);
    float s = z0 * (1.0f - f0);
    out[(size_t)b * (T_ + 1) * H_ + h] = s;
    float flp = f0;
#pragma unroll 4
    for (int c = 0; c < NC; ++c) {
        float st = flp * s;
        sin_[((size_t)b * NC + c) * H_ + h] = st;
        unsigned u = AP[((size_t)b * T_ + c * TC + (TC - 1)) * H_ + h];
        s = fmaf(bf2f((ushort)(u >> 16)), st, bf2f((ushort)(u & 0xffff)));
        flp = fl[((size_t)b * NC + c) * H_ + h];
    }
}

// out_{r0+1+j} = A_j + P'_j * s~_c   (fully parallel)
__global__ __launch_bounds__(256) void apply_kernel(const unsigned* __restrict__ AP,
                                                    const float* __restrict__ sin_,
                                                    float* __restrict__ out) {
    const int c = blockIdx.x;
    const int b = blockIdx.y;
    const int h = threadIdx.x;
    const int r0 = c * TC;
    const float s = sin_[((size_t)b * NC + c) * H_ + h];
    const unsigned* app = AP + ((size_t)b * T_ + r0) * H_ + h;
    float* op = out + ((size_t)b * (T_ + 1) + r0 + 1) * H_ + h;
#pragma unroll 8
    for (int j = 0; j < TC; ++j) {
        unsigned u = app[(size_t)j * H_];
        op[(size_t)j * H_] = fmaf(bf2f((ushort)(u >> 16)), s, bf2f((ushort)(u & 0xffff)));
    }
}

extern "C" void kernel_launch(void* const* d_in, const int* in_sizes, int n_in,
                              void* d_out, int out_size, void* d_ws, size_t ws_size,
                              hipStream_t stream) {
    const float* inputs = (const float*)d_in[0];   // [B,T,C]
    const float* init_f = (const float*)d_in[1];   // [B,H]
    const float* init_z = (const float*)d_in[2];   // [B,H]
    const float* f_w    = (const float*)d_in[3];   // [H,C,K]
    const float* f_b    = (const float*)d_in[4];   // [H]
    const float* z_w    = (const float*)d_in[5];   // [H,C,K]
    const float* z_b    = (const float*)d_in[6];   // [H]
    float* out = (float*)d_out;                    // [B,T+1,H]

    // ws: wfrag 768KB | AP (B*T*H uint, 32MB) | fl 1MB | sin 1MB
    ushort* wfrag = (ushort*)d_ws;
    unsigned* AP  = (unsigned*)(wfrag + WFRAG_ELEMS);
    float* fl     = (float*)(AP + (size_t)B_ * T_ * H_);
    float* sin_   = fl + (size_t)B_ * NC * H_;

    wfrag_kernel<<<(WFRAG_ELEMS + 255) / 256, 256, 0, stream>>>(f_w, z_w, wfrag);

    dim3 cgrid(T_ / 64, B_, 1);
    conv_scan_kernel<<<cgrid, 512, 0, stream>>>(inputs, wfrag, f_b, z_b, AP, fl);

    combine_kernel<<<B_, H_, 0, stream>>>(AP, fl, init_f, init_z, out, sin_);

    dim3 agrid(NC, B_, 1);
    apply_kernel<<<agrid, 256, 0, stream>>>(AP, sin_, out);
}